// Round 3
// baseline (1049.428 us; speedup 1.0000x reference)
//
#include <hip/hip_runtime.h>

#define N_NODES 100000
#define N_EDGES 3200000
#define D_IN    512
#define D_HID   16
#define N_CLS   7
#define D_PAD   8

// ---------------- zero int array ----------------
__global__ __launch_bounds__(256) void zero_i(int* __restrict__ p, int n) {
    int i = blockIdx.x * 256 + threadIdx.x;
    if (i < n) p[i] = 0;
}

// ---------------- degree histogram: deg[dst[e]]++ ----------------
__global__ __launch_bounds__(256) void hist(const int* __restrict__ dst,
                                            int* __restrict__ deg) {
    int e = blockIdx.x * 256 + threadIdx.x;
    if (e < N_EDGES) atomicAdd(&deg[dst[e]], 1);
}

// ---------------- exclusive scan of deg -> offs (and cursor copy) ----------
// Single block, 1024 threads, 98 elems/thread serial + Hillis-Steele on partials.
__global__ __launch_bounds__(1024) void scan_offs(const int* __restrict__ deg,
                                                  int* __restrict__ offs,
                                                  int* __restrict__ cursor) {
    __shared__ int part[1024];
    const int CH = (N_NODES + 1023) / 1024;   // 98
    int t = threadIdx.x;
    int base = t * CH;
    int s = 0;
    for (int i = 0; i < CH; ++i) {
        int idx = base + i;
        if (idx < N_NODES) s += deg[idx];
    }
    part[t] = s;
    __syncthreads();
    for (int off = 1; off < 1024; off <<= 1) {
        int v = 0;
        if (t >= off) v = part[t - off];
        __syncthreads();
        part[t] += v;
        __syncthreads();
    }
    int run = (t == 0) ? 0 : part[t - 1];     // exclusive prefix of this chunk
    for (int i = 0; i < CH; ++i) {
        int idx = base + i;
        if (idx < N_NODES) {
            offs[idx] = run;
            cursor[idx] = run;
            run += deg[idx];
        }
    }
    if (t == 1023) offs[N_NODES] = part[1023];  // = N_EDGES
}

// ---------------- fill CSR: esrc[slot] = src, grouped by dst ----------------
__global__ __launch_bounds__(256) void fill_csr(const int* __restrict__ src,
                                                const int* __restrict__ dst,
                                                int* __restrict__ cursor,
                                                int* __restrict__ esrc) {
    int e = blockIdx.x * 256 + threadIdx.x;
    if (e >= N_EDGES) return;
    int d = dst[e];
    int slot = atomicAdd(&cursor[d], 1);
    esrc[slot] = src[e];
}

// ---------------- h1 = x @ W1  (100000x512 @ 512x16) ----------------
__global__ __launch_bounds__(256) void gemm1(const float* __restrict__ x,
                                             const float* __restrict__ W1,
                                             float* __restrict__ h1) {
    __shared__ float4 w4s[D_IN * 4];          // 32 KB
    const float4* W1f4 = (const float4*)W1;
    int t = threadIdx.x;
#pragma unroll
    for (int i = 0; i < 8; ++i) w4s[i * 256 + t] = W1f4[i * 256 + t];
    __syncthreads();

    int jq  = t & 3;
    int r   = t >> 2;
    int row = blockIdx.x * 64 + r;
    if (row >= N_NODES) return;

    const float4* xr = (const float4*)(x + (size_t)row * D_IN);
    float4 acc = make_float4(0.f, 0.f, 0.f, 0.f);

#pragma unroll 4
    for (int k4 = 0; k4 < D_IN / 4; ++k4) {
        float4 xv = xr[k4];
        float4 w0 = w4s[(k4 * 4 + 0) * 4 + jq];
        float4 w1 = w4s[(k4 * 4 + 1) * 4 + jq];
        float4 w2 = w4s[(k4 * 4 + 2) * 4 + jq];
        float4 w3 = w4s[(k4 * 4 + 3) * 4 + jq];
        acc.x = fmaf(xv.x, w0.x, acc.x); acc.y = fmaf(xv.x, w0.y, acc.y);
        acc.z = fmaf(xv.x, w0.z, acc.z); acc.w = fmaf(xv.x, w0.w, acc.w);
        acc.x = fmaf(xv.y, w1.x, acc.x); acc.y = fmaf(xv.y, w1.y, acc.y);
        acc.z = fmaf(xv.y, w1.z, acc.z); acc.w = fmaf(xv.y, w1.w, acc.w);
        acc.x = fmaf(xv.z, w2.x, acc.x); acc.y = fmaf(xv.z, w2.y, acc.y);
        acc.z = fmaf(xv.z, w2.z, acc.z); acc.w = fmaf(xv.z, w2.w, acc.w);
        acc.x = fmaf(xv.w, w3.x, acc.x); acc.y = fmaf(xv.w, w3.y, acc.y);
        acc.z = fmaf(xv.w, w3.z, acc.z); acc.w = fmaf(xv.w, w3.w, acc.w);
    }
    ((float4*)(h1 + (size_t)row * D_HID))[jq] = acc;
}

// ---------------- gather-aggregate layer 1: agg[n][j] = sum h1[src][j] ------
// thread = (node_local, j): 16 nodes x 16 features per block.
__global__ __launch_bounds__(256) void gather1(const int* __restrict__ offs,
                                               const int* __restrict__ esrc,
                                               const float* __restrict__ h1,
                                               float* __restrict__ agg) {
    int t = threadIdx.x;
    int j = t & 15, ln = t >> 4;
    int node = blockIdx.x * 16 + ln;
    if (node >= N_NODES) return;
    int k0 = offs[node], k1 = offs[node + 1];
    float sum = 0.f;
    int k = k0;
    for (; k + 1 < k1; k += 2) {
        int s0 = esrc[k];
        int s1 = esrc[k + 1];
        float a = h1[s0 * D_HID + j];
        float b = h1[s1 * D_HID + j];
        sum += a;
        sum += b;
    }
    if (k < k1) sum += h1[esrc[k] * D_HID + j];
    agg[node * D_HID + j] = sum;
}

// ---------------- h2p = pad8( relu(agg + b1) @ W2 ) ----------------
__global__ __launch_bounds__(256) void layer2(const float* __restrict__ agg,
                                              const float* __restrict__ b1,
                                              const float* __restrict__ W2,
                                              float* __restrict__ h2p) {
    __shared__ float w2s[D_HID * N_CLS];
    __shared__ float b1s[D_HID];
    int t = threadIdx.x;
    if (t < D_HID * N_CLS) w2s[t] = W2[t];
    if (t < D_HID) b1s[t] = b1[t];
    __syncthreads();

    int n = blockIdx.x * 256 + t;
    if (n >= N_NODES) return;

    const float4* a4 = (const float4*)(agg + (size_t)n * D_HID);
    float rel[D_HID];
#pragma unroll
    for (int q = 0; q < 4; ++q) {
        float4 v = a4[q];
        rel[4 * q + 0] = fmaxf(v.x + b1s[4 * q + 0], 0.f);
        rel[4 * q + 1] = fmaxf(v.y + b1s[4 * q + 1], 0.f);
        rel[4 * q + 2] = fmaxf(v.z + b1s[4 * q + 2], 0.f);
        rel[4 * q + 3] = fmaxf(v.w + b1s[4 * q + 3], 0.f);
    }
    float o[D_PAD];
#pragma unroll
    for (int c = 0; c < D_PAD; ++c) o[c] = 0.f;
#pragma unroll
    for (int j = 0; j < D_HID; ++j) {
#pragma unroll
        for (int c = 0; c < N_CLS; ++c)
            o[c] = fmaf(rel[j], w2s[j * N_CLS + c], o[c]);
    }
    float4* hp = (float4*)(h2p + (size_t)n * D_PAD);
    hp[0] = make_float4(o[0], o[1], o[2], o[3]);
    hp[1] = make_float4(o[4], o[5], o[6], 0.f);
}

// ---------------- gather layer 2 + bias: out[n][c] = b2[c] + sum h2p[src][c] -
// thread = (node_local, j): 32 nodes x 8 lanes per block; lane 7 idle on write.
__global__ __launch_bounds__(256) void gather2(const int* __restrict__ offs,
                                               const int* __restrict__ esrc,
                                               const float* __restrict__ h2p,
                                               const float* __restrict__ b2,
                                               float* __restrict__ out) {
    int t = threadIdx.x;
    int j = t & 7, ln = t >> 3;
    int node = blockIdx.x * 32 + ln;
    if (node >= N_NODES) return;
    int k0 = offs[node], k1 = offs[node + 1];
    float sum = 0.f;
    int k = k0;
    for (; k + 1 < k1; k += 2) {
        int s0 = esrc[k];
        int s1 = esrc[k + 1];
        float a = h2p[s0 * D_PAD + j];
        float b = h2p[s1 * D_PAD + j];
        sum += a;
        sum += b;
    }
    if (k < k1) sum += h2p[esrc[k] * D_PAD + j];
    if (j < N_CLS) out[(size_t)node * N_CLS + j] = sum + b2[j];
}

extern "C" void kernel_launch(void* const* d_in, const int* in_sizes, int n_in,
                              void* d_out, int out_size, void* d_ws, size_t ws_size,
                              hipStream_t stream) {
    const float* x  = (const float*)d_in[0];
    const int*   ei = (const int*)d_in[1];
    const float* W1 = (const float*)d_in[2];
    const float* b1 = (const float*)d_in[3];
    const float* W2 = (const float*)d_in[4];
    const float* b2 = (const float*)d_in[5];
    float* out = (float*)d_out;

    char* ws = (char*)d_ws;
    float* h1     = (float*)(ws);                    //  6,400,000 B
    float* agg1   = (float*)(ws + 6400000);          //  6,400,000 B
    float* h2p    = (float*)(ws + 12800000);         //  3,200,000 B
    int*   deg    = (int*)  (ws + 16000000);         //    400,000 B
    int*   offs   = (int*)  (ws + 16400000);         //    400,032 B (N+1 ints)
    int*   cursor = (int*)  (ws + 16800032);         //    400,000 B
    int*   esrc   = (int*)  (ws + 17200032);         // 12,800,000 B  -> total ~30 MB

    const int* src = ei;             // edge_index[0]
    const int* dst = ei + N_EDGES;   // edge_index[1]

    // CSR build (grouped by dst)
    zero_i   <<<(N_NODES + 255) / 256, 256, 0, stream>>>(deg, N_NODES);
    hist     <<<(N_EDGES + 255) / 256, 256, 0, stream>>>(dst, deg);
    scan_offs<<<1, 1024, 0, stream>>>(deg, offs, cursor);
    fill_csr <<<(N_EDGES + 255) / 256, 256, 0, stream>>>(src, dst, cursor, esrc);

    // h1 = x @ W1
    gemm1<<<(N_NODES + 63) / 64, 256, 0, stream>>>(x, W1, h1);

    // agg1 = gather-sum h1 over in-edges
    gather1<<<(N_NODES + 15) / 16, 256, 0, stream>>>(offs, esrc, h1, agg1);

    // h2p = relu(agg1 + b1) @ W2, padded to 8
    layer2<<<(N_NODES + 255) / 256, 256, 0, stream>>>(agg1, b1, W2, h2p);

    // out = b2 + gather-sum h2p over in-edges
    gather2<<<(N_NODES + 31) / 32, 256, 0, stream>>>(offs, esrc, h2p, b2, out);
}

// Round 4
// 756.964 us; speedup vs baseline: 1.3864x; 1.3864x over previous
//
#include <hip/hip_runtime.h>

#define N_NODES 100000
#define N_EDGES 3200000
#define D_IN    512
#define D_HID   16
#define N_CLS   7
#define D_PAD   8

#define NB        512                 // dst-range buckets
#define NODES_PER 196                 // ceil(N_NODES / NB)
#define BCAP      8192                // per-bucket capacity (mean 6272, sd 79)
#define FILL_CHUNK 16384
#define FILL_WGS  ((N_EDGES + FILL_CHUNK - 1) / FILL_CHUNK)   // 196

// ---------------- cursor init: cursor[b] = b * BCAP ----------------
__global__ __launch_bounds__(512) void cursor_init(int* __restrict__ cursor) {
    cursor[threadIdx.x] = (int)threadIdx.x * BCAP;
}

// ---------------- bucket fill: packed[slot] = src | (local_dst << 17) -------
// Per-WG LDS histogram -> one global reservation per (WG,bucket) -> ranked
// writes. Writes within a bucket advance near-sequentially => L2 combines.
__global__ __launch_bounds__(1024) void bucket_fill(const int* __restrict__ src,
                                                    const int* __restrict__ dst,
                                                    int* __restrict__ cursor,
                                                    unsigned int* __restrict__ packed) {
    __shared__ int bcnt[NB];
    __shared__ int bcur[NB];
    int t = threadIdx.x;
    if (t < NB) bcnt[t] = 0;
    __syncthreads();

    int base_e = blockIdx.x * FILL_CHUNK;
#pragma unroll
    for (int i = 0; i < FILL_CHUNK / 1024; ++i) {
        int e = base_e + i * 1024 + t;
        if (e < N_EDGES) atomicAdd(&bcnt[dst[e] / NODES_PER], 1);
    }
    __syncthreads();

    if (t < NB) {
        int c = bcnt[t];
        bcur[t] = (c > 0) ? atomicAdd(&cursor[t], c) : 0;
    }
    __syncthreads();

#pragma unroll
    for (int i = 0; i < FILL_CHUNK / 1024; ++i) {
        int e = base_e + i * 1024 + t;
        if (e < N_EDGES) {
            int d = dst[e];
            int b = d / NODES_PER;
            int loc = d - b * NODES_PER;
            int r = atomicAdd(&bcur[b], 1);
            packed[r] = (unsigned)src[e] | ((unsigned)loc << 17);
        }
    }
}

// ---------------- h1 = x @ W1  (100000x512 @ 512x16) ----------------
__global__ __launch_bounds__(256) void gemm1(const float* __restrict__ x,
                                             const float* __restrict__ W1,
                                             float* __restrict__ h1) {
    __shared__ float4 w4s[D_IN * 4];          // 32 KB
    const float4* W1f4 = (const float4*)W1;
    int t = threadIdx.x;
#pragma unroll
    for (int i = 0; i < 8; ++i) w4s[i * 256 + t] = W1f4[i * 256 + t];
    __syncthreads();

    int jq  = t & 3;
    int r   = t >> 2;
    int row = blockIdx.x * 64 + r;
    if (row >= N_NODES) return;

    const float4* xr = (const float4*)(x + (size_t)row * D_IN);
    float4 acc = make_float4(0.f, 0.f, 0.f, 0.f);

#pragma unroll 4
    for (int k4 = 0; k4 < D_IN / 4; ++k4) {
        float4 xv = xr[k4];
        float4 w0 = w4s[(k4 * 4 + 0) * 4 + jq];
        float4 w1 = w4s[(k4 * 4 + 1) * 4 + jq];
        float4 w2 = w4s[(k4 * 4 + 2) * 4 + jq];
        float4 w3 = w4s[(k4 * 4 + 3) * 4 + jq];
        acc.x = fmaf(xv.x, w0.x, acc.x); acc.y = fmaf(xv.x, w0.y, acc.y);
        acc.z = fmaf(xv.x, w0.z, acc.z); acc.w = fmaf(xv.x, w0.w, acc.w);
        acc.x = fmaf(xv.y, w1.x, acc.x); acc.y = fmaf(xv.y, w1.y, acc.y);
        acc.z = fmaf(xv.y, w1.z, acc.z); acc.w = fmaf(xv.y, w1.w, acc.w);
        acc.x = fmaf(xv.z, w2.x, acc.x); acc.y = fmaf(xv.z, w2.y, acc.y);
        acc.z = fmaf(xv.z, w2.z, acc.z); acc.w = fmaf(xv.z, w2.w, acc.w);
        acc.x = fmaf(xv.w, w3.x, acc.x); acc.y = fmaf(xv.w, w3.y, acc.y);
        acc.z = fmaf(xv.w, w3.z, acc.z); acc.w = fmaf(xv.w, w3.w, acc.w);
    }
    ((float4*)(h1 + (size_t)row * D_HID))[jq] = acc;
}

// -------- agg1 (LDS accumulate) fused with layer2: h2p = pad8(relu(agg+b1)@W2)
__global__ __launch_bounds__(1024) void agg1_layer2(const unsigned int* __restrict__ packed,
                                                    const int* __restrict__ cursor,
                                                    const float* __restrict__ h1,
                                                    const float* __restrict__ b1,
                                                    const float* __restrict__ W2,
                                                    float* __restrict__ h2p) {
    __shared__ float acc[NODES_PER * D_HID];   // 12.5 KB
    __shared__ float w2s[D_HID * N_CLS];
    __shared__ float b1s[D_HID];
    int t = threadIdx.x;
    if (t < D_HID * N_CLS) w2s[t] = W2[t];
    if (t >= 128 && t < 128 + D_HID) b1s[t - 128] = b1[t - 128];
    for (int i = t; i < NODES_PER * D_HID; i += 1024) acc[i] = 0.f;
    __syncthreads();

    int b  = blockIdx.x;
    int e0 = b * BCAP;
    int e1 = cursor[b];
    int g  = t >> 4;          // 64 edge-groups of 16 lanes
    int j  = t & 15;
    for (int k = e0 + g; k < e1; k += 64) {
        unsigned p = packed[k];
        int s   = p & 0x1FFFF;
        int loc = p >> 17;
        atomicAdd(&acc[loc * D_HID + j], h1[(size_t)s * D_HID + j]);
    }
    __syncthreads();

    int nbase = b * NODES_PER;
    int nn = N_NODES - nbase; if (nn > NODES_PER) nn = NODES_PER;
    if ((int)t < nn) {
        float o[N_CLS];
#pragma unroll
        for (int c = 0; c < N_CLS; ++c) o[c] = 0.f;
#pragma unroll
        for (int jj = 0; jj < D_HID; ++jj) {
            float r = fmaxf(acc[t * D_HID + jj] + b1s[jj], 0.f);
#pragma unroll
            for (int c = 0; c < N_CLS; ++c)
                o[c] = fmaf(r, w2s[jj * N_CLS + c], o[c]);
        }
        float4* hp = (float4*)(h2p + (size_t)(nbase + t) * D_PAD);
        hp[0] = make_float4(o[0], o[1], o[2], o[3]);
        hp[1] = make_float4(o[4], o[5], o[6], 0.f);
    }
}

// -------- agg2 (LDS accumulate) fused with +b2: out = gather-sum(h2p) + b2 ---
__global__ __launch_bounds__(1024) void agg2_out(const unsigned int* __restrict__ packed,
                                                 const int* __restrict__ cursor,
                                                 const float* __restrict__ h2p,
                                                 const float* __restrict__ b2,
                                                 float* __restrict__ out) {
    __shared__ float acc[NODES_PER * D_PAD];   // 6.3 KB
    __shared__ float b2s[N_CLS];
    int t = threadIdx.x;
    if (t < N_CLS) b2s[t] = b2[t];
    for (int i = t; i < NODES_PER * D_PAD; i += 1024) acc[i] = 0.f;
    __syncthreads();

    int b  = blockIdx.x;
    int e0 = b * BCAP;
    int e1 = cursor[b];
    int g  = t >> 3;          // 128 edge-groups of 8 lanes
    int j  = t & 7;
    for (int k = e0 + g; k < e1; k += 128) {
        unsigned p = packed[k];
        int s   = p & 0x1FFFF;
        int loc = p >> 17;
        atomicAdd(&acc[loc * D_PAD + j], h2p[(size_t)s * D_PAD + j]);
    }
    __syncthreads();

    int nbase = b * NODES_PER;
    int nn = N_NODES - nbase; if (nn > NODES_PER) nn = NODES_PER;
    if (nn > 0) {
        int total = nn * N_CLS;
        float* obase = out + (size_t)nbase * N_CLS;
        for (int i = t; i < total; i += 1024) {
            int node = i / N_CLS;
            int c = i - node * N_CLS;
            obase[i] = acc[node * D_PAD + c] + b2s[c];
        }
    }
}

extern "C" void kernel_launch(void* const* d_in, const int* in_sizes, int n_in,
                              void* d_out, int out_size, void* d_ws, size_t ws_size,
                              hipStream_t stream) {
    const float* x  = (const float*)d_in[0];
    const int*   ei = (const int*)d_in[1];
    const float* W1 = (const float*)d_in[2];
    const float* b1 = (const float*)d_in[3];
    const float* W2 = (const float*)d_in[4];
    const float* b2 = (const float*)d_in[5];
    float* out = (float*)d_out;

    char* ws = (char*)d_ws;
    float*        h1     = (float*)(ws);                       //  6,400,000 B
    float*        h2p    = (float*)(ws + 6400000);             //  3,200,000 B
    unsigned int* packed = (unsigned int*)(ws + 9600000);      // 16,777,216 B
    int*          cursor = (int*)(ws + 26377216);              //      2,048 B

    const int* src = ei;             // edge_index[0]
    const int* dst = ei + N_EDGES;   // edge_index[1]

    cursor_init<<<1, 512, 0, stream>>>(cursor);
    bucket_fill<<<FILL_WGS, 1024, 0, stream>>>(src, dst, cursor, packed);
    gemm1<<<(N_NODES + 63) / 64, 256, 0, stream>>>(x, W1, h1);
    agg1_layer2<<<NB, 1024, 0, stream>>>(packed, cursor, h1, b1, W2, h2p);
    agg2_out<<<NB, 1024, 0, stream>>>(packed, cursor, h2p, b2, out);
}